// Round 10
// baseline (6500.248 us; speedup 1.0000x reference)
//
#include <hip/hip_runtime.h>

// ---------------------------------------------------------------------------
// Persistent weight-stationary LSTM, bf16 MFMA, DECOUPLED per-layer sync.
// T=1024 B=64 C=256 H=512, 2 layers, fp32 in/out.
//  - 256 blocks x 256 threads, 1 block/CU; blocks 0..127 = layer0 (step s),
//    128..255 = layer1 (step s). NO full-grid barrier.
//  - h0 = 4-deep ring (ws permitting; else 2-deep, same code): L0 step s
//    waits gen0>=s && gen1>=s-3; L1 step s waits gen1>=s && gen0>=s+1.
//    Steady state: L0 runs 3 ahead -> L1's cross-wait pre-satisfied; each
//    group's period = own 128-block chain; cross-layer skew absorbed by
//    ring slack (R4 serialized max-over-256 skew into every tick).
//  - Sync (R4-disciplined, ~768 poll loads/round total):
//      arrival: vmcnt(0) drain -> syncthreads -> tid0 flags slot[bid].
//      aggregators: block0 scans slots 0..127 (wave0, 2/lane) -> gen0 x4
//      lines; block128 scans 128..255 -> gen1. Publish BEFORE cross-poll
//      (unconditional publication -> no deadlock).
//      workers: tid0 polls own-gen + cross-gen lines only.
//  - Compute core byte-identical to R4: FragLd sc0sc1 one-LLC-round loads,
//    pinned weight frags, pack8 x-projection, shuffle-gather epilogue.
//  - mfma_f32_16x16x32_bf16: A[m=lane&15][k=quad*8+j], B(N,K)[n=lane&15][k=quad*8+j],
//    D[m=quad*4+reg][n=lane&15]  (guide-verified mapping, m90/m97 convention)
// ---------------------------------------------------------------------------

#define TT 1024
#define BB 64
#define CC 256
#define HH 512
#define Y_ELEMS (TT * BB * HH)
#define S_ELEMS (BB * HH)

typedef __attribute__((ext_vector_type(8))) short bf16x8;
typedef __attribute__((ext_vector_type(4))) float f32x4;
typedef unsigned int u32;
typedef unsigned short u16;
typedef unsigned long long u64;

// ---- ws layout (bytes) ----
#define WS_BAR 0            // 256 slots * 128B
#define WS_GEN 32768        // 8 gen lines * 128B (gen0: 0..3, gen1: 4..7)
#define WS_BSUM0 36864      // 2048 f32
#define WS_BSUM1 45056      // 2048 f32
#define WS_H0 53248         // h0 ring slots (65536 B each; 4 deep ends 315392)
#define WS_WPK0 315392      // 128*24*64*8 bf16 (3,145,728 B)
#define WS_WPK1 3461120     // 128*32*64*8 bf16 (4,194,304 B) -> ends 7,655,424
#define H_SLOT_BYTES 65536
// 4-deep mode: h1 (2 slots) at 7,655,424 -> end 7,786,496
// 2-deep mode: h1 at 184,320 (R4 layout) -> end 7,655,424

__device__ __forceinline__ u16 f2b_rne(float f) {
    u32 u = __float_as_uint(f);
    return (u16)((u + 0x7FFFu + ((u >> 16) & 1u)) >> 16);
}
__device__ __forceinline__ u16 f2b_fast(float f) {  // round-half-up, 2 ops
    return (u16)((__float_as_uint(f) + 0x8000u) >> 16);
}
__device__ __forceinline__ float sigf(float z) { return 1.0f / (1.0f + __expf(-z)); }
__device__ __forceinline__ float tanh_f(float z) { return 2.0f / (1.0f + __expf(-2.0f * z)) - 1.0f; }

__device__ __forceinline__ bf16x8 pack8(float4 a, float4 b) {
    union { u16 u[8]; bf16x8 v; } r;
    r.u[0] = f2b_fast(a.x); r.u[1] = f2b_fast(a.y); r.u[2] = f2b_fast(a.z); r.u[3] = f2b_fast(a.w);
    r.u[4] = f2b_fast(b.x); r.u[5] = f2b_fast(b.y); r.u[6] = f2b_fast(b.z); r.u[7] = f2b_fast(b.w);
    return r.v;
}

__device__ __forceinline__ u32 ld_u32_sc(const u32* p) {
    return __hip_atomic_load(p, __ATOMIC_RELAXED, __HIP_MEMORY_SCOPE_AGENT);
}
__device__ __forceinline__ void st_u32_sc(u32* p, u32 v) {
    __hip_atomic_store(p, v, __ATOMIC_RELAXED, __HIP_MEMORY_SCOPE_AGENT);
}
__device__ __forceinline__ void st_h_sc(u16* p, u16 v) {
    __hip_atomic_store(p, v, __ATOMIC_RELAXED, __HIP_MEMORY_SCOPE_AGENT);
}

// N cache-bypassing 16B loads, base + compile-time offsets, back-to-back,
// forced-live destinations -> one LLC latency round.  (R4-proven)
template <int I, int N>
struct FragLd {
    static __device__ __forceinline__ void go(f32x4* d, const u16* p) {
        asm volatile("global_load_dwordx4 %0, %1, off offset:%c2 sc0 sc1"
                     : "=&v"(d[I]) : "v"(p), "n"(I * 64) : "memory");
        FragLd<I + 1, N>::go(d, p);
    }
};
template <int N>
struct FragLd<N, N> {
    static __device__ __forceinline__ void go(f32x4*, const u16*) {}
};

// ---- init: zero flags+gens, bsum = bih+bhh, h slot0 <- bf16(initial h) ----
__global__ void k_init(const float* __restrict__ bih0, const float* __restrict__ bhh0,
                       const float* __restrict__ bih1, const float* __restrict__ bhh1,
                       const float* __restrict__ h00, const float* __restrict__ h01,
                       unsigned char* __restrict__ ws, u64 h1off) {
    u32* bar = (u32*)(ws + WS_BAR);
    float* bs0 = (float*)(ws + WS_BSUM0);
    float* bs1 = (float*)(ws + WS_BSUM1);
    u16* h0 = (u16*)(ws + WS_H0);
    u16* h1 = (u16*)(ws + h1off);
    int t = blockIdx.x * 256 + threadIdx.x;  // 32768 threads
    if (t < 8448) bar[t] = 0u;               // slots + gen lines
    if (t < 2048) { bs0[t] = bih0[t] + bhh0[t]; bs1[t] = bih1[t] + bhh1[t]; }
    if (t < S_ELEMS) { h0[t] = f2b_rne(h00[t]); h1[t] = f2b_rne(h01[t]); }
}

// ---- weight pack: fp32 [4H,K] -> bf16 B-frag order wpk[bidL][kt][lane][8] ----
// rows permuted: n-index (lane&15) = gg*4+jj  <->  W row = gg*512 + bidL*4 + jj
__global__ void k_wprep(const float* __restrict__ Wih0, const float* __restrict__ Whh0,
                        const float* __restrict__ Wih1, const float* __restrict__ Whh1,
                        unsigned char* __restrict__ ws) {
    u16* wpk0 = (u16*)(ws + WS_WPK0);
    u16* wpk1 = (u16*)(ws + WS_WPK1);
    int u = blockIdx.x * 256 + threadIdx.x;  // 458752 threads
    const float* s;
    u16* d;
    if (u < 128 * 24 * 64) {  // layer0: 8 x-tiles (K=256) + 16 h-tiles (K=512)
        int bidL = u / (24 * 64);
        int kt = (u >> 6) % 24;
        int lane = u & 63;
        int n = lane & 15, quad = lane >> 4;
        int row = (n >> 2) * 512 + bidL * 4 + (n & 3);
        int k = kt * 32 + quad * 8;
        s = (k < 256) ? (Wih0 + (size_t)row * 256 + k) : (Whh0 + (size_t)row * 512 + (k - 256));
        d = wpk0 + (size_t)((bidL * 24 + kt) * 64 + lane) * 8;
    } else {  // layer1: 16 y0-tiles + 16 h1-tiles (K=1024)
        int v = u - 128 * 24 * 64;
        int bidL = v / (32 * 64);
        int kt = (v >> 6) % 32;
        int lane = v & 63;
        int n = lane & 15, quad = lane >> 4;
        int row = (n >> 2) * 512 + bidL * 4 + (n & 3);
        int k = kt * 32 + quad * 8;
        s = (k < 512) ? (Wih1 + (size_t)row * 512 + k) : (Whh1 + (size_t)row * 512 + (k - 512));
        d = wpk1 + (size_t)((bidL * 32 + kt) * 64 + lane) * 8;
    }
    #pragma unroll
    for (int i = 0; i < 8; ++i) d[i] = f2b_rne(s[i]);
}

// ---- the persistent per-layer step loop ----
// m0 = h0 ring mask (3 => 4-deep, slack 3; 1 => 2-deep, slack 1)
template <int LAYER>
__device__ void run_ticks(const float* __restrict__ x, const float* __restrict__ c0,
                          float* __restrict__ out, unsigned char* __restrict__ ws,
                          int bidL, u32 m0, u64 h1off) {
    constexpr int NKT = (LAYER == 0) ? 24 : 32;
    u32* slots = (u32*)(ws + WS_BAR);
    u32* gen0 = (u32*)(ws + WS_GEN);          // 4 lines, stride 32 u32
    u32* gen1 = gen0 + 4 * 32;                // 4 lines
    const float* bs = (const float*)(ws + (LAYER == 0 ? WS_BSUM0 : WS_BSUM1));
    u16* h0base = (u16*)(ws + WS_H0);
    u16* h1base = (u16*)(ws + h1off);
    const u16* wpk = (const u16*)(ws + (LAYER == 0 ? WS_WPK0 : WS_WPK1));

    const int tid = threadIdx.x, lane = tid & 63, wave = tid >> 6;
    const int r16 = lane & 15, quad = lane >> 4, q8 = quad * 8;
    const int gg = r16 >> 2, jj = r16 & 3;
    const int b0 = wave * 16;
    const int col = bidL * 4 + jj;            // h column this lane finalizes
    const int myb = b0 + quad * 4 + gg;       // batch this lane finalizes
    const int sl0 = (quad << 4) | (0 << 2) | jj;
    const int sl1 = (quad << 4) | (1 << 2) | jj;
    const int sl2 = (quad << 4) | (2 << 2) | jj;
    const int sl3 = (quad << 4) | (3 << 2) | jj;

    const bool AGG = (bidL == 0);                 // block 0 / block 128
    const int groupBase = (LAYER == 0) ? 0 : 128; // own group's slot base
    u32* genOwn = (LAYER == 0) ? gen0 : gen1;
    const u32* gOwnP = genOwn + ((u32)blockIdx.x & 3) * 32;
    const u32* gCrossP = ((LAYER == 0) ? gen1 : gen0) + ((u32)blockIdx.x & 3) * 32;

    // biases (hoisted), c state in register for the whole run
    const float bi = bs[0 * HH + col], bf_ = bs[1 * HH + col];
    const float bg = bs[2 * HH + col], bo = bs[3 * HH + col];
    float c = c0[myb * HH + col];

    // weight fragments: load once; reloads (if rematerialized) hit L1/L2
    f32x4 wf[NKT];
    {
        const u16* wp = wpk + (size_t)(bidL * NKT * 64 + lane) * 8;
        #pragma unroll
        for (int kt = 0; kt < NKT; ++kt) wf[kt] = *(const f32x4*)(wp + (size_t)kt * 64 * 8);
        #pragma unroll
        for (int kt = 0; kt < NKT; ++kt) asm volatile("" : "+v"(wf[kt]));
    }

    // layer0: x prefetch registers (step 0 issued before the loop)
    float4 xf0[8], xf1[8];
    if (LAYER == 0) {
        const float* xp = x + (size_t)(b0 + r16) * CC + q8;
        #pragma unroll
        for (int kt = 0; kt < 8; ++kt) {
            xf0[kt] = *(const float4*)(xp + kt * 32);
            xf1[kt] = *(const float4*)(xp + kt * 32 + 4);
        }
    }

    for (int s = 0; s < TT; ++s) {
        // ---- WAIT: own group done step s-1; cross-layer ring constraint ----
        const u32 needOwn = (u32)s;
        const u32 needCross = (LAYER == 0)
            ? (u32)((s > (int)m0) ? (s - (int)m0) : 0)   // L1 finished step s-1-m0
            : (u32)(s + 1);                              // L0 finished step s
        if (AGG) {
            if (tid < 64) {  // wave0 scans own group's 128 slots, 2 per lane
                const u32* p0 = slots + ((u32)(groupBase + tid * 2 + 0)) * 32;
                const u32* p1 = slots + ((u32)(groupBase + tid * 2 + 1)) * 32;
                u32 m;
                do {
                    u32 va = ld_u32_sc(p0);
                    u32 vb = ld_u32_sc(p1);
                    m = min(va, vb);
                } while (m < needOwn);
            }
            __syncthreads();
            if (tid == 0) {
                // publish FIRST (unconditional -> the other layer never deadlocks
                // on our cross-wait), then poll cross.
                #pragma unroll
                for (int k2 = 0; k2 < 4; ++k2) st_u32_sc(genOwn + k2 * 32, needOwn);
                while (ld_u32_sc(gCrossP) < needCross) { }
            }
            __syncthreads();
        } else {
            if (tid == 0) {
                while (ld_u32_sc(gOwnP) < needOwn || ld_u32_sc(gCrossP) < needCross) { }
            }
            __syncthreads();
        }

        // ---- COMPUTE step s (byte-identical to R4 core) ----
        f32x4 a0 = {0.f,0.f,0.f,0.f}, a1 = {0.f,0.f,0.f,0.f};
        f32x4 a2 = {0.f,0.f,0.f,0.f}, a3 = {0.f,0.f,0.f,0.f};
        if (LAYER == 0) {
            f32x4 afr[16];
            const u16* hp = h0base + (size_t)((u32)s & m0) * S_ELEMS
                          + (size_t)(b0 + r16) * HH + q8;
            FragLd<0, 16>::go(afr, hp);
            #pragma unroll
            for (int kt = 0; kt < 8; ++kt) {      // x proj overlaps h-load flight
                bf16x8 a = pack8(xf0[kt], xf1[kt]);
                bf16x8 wv = __builtin_bit_cast(bf16x8, wf[kt]);
                f32x4& dst = (kt & 2) ? ((kt & 1) ? a3 : a2) : ((kt & 1) ? a1 : a0);
                dst = __builtin_amdgcn_mfma_f32_16x16x32_bf16(a, wv, dst, 0, 0, 0);
            }
            asm volatile("s_waitcnt vmcnt(0)" ::: "memory");
            __builtin_amdgcn_sched_barrier(0);
            #pragma unroll
            for (int kt = 0; kt < 16; ++kt) {
                bf16x8 av = __builtin_bit_cast(bf16x8, afr[kt]);
                bf16x8 wv = __builtin_bit_cast(bf16x8, wf[8 + kt]);
                f32x4& dst = (kt & 2) ? ((kt & 1) ? a3 : a2) : ((kt & 1) ? a1 : a0);
                dst = __builtin_amdgcn_mfma_f32_16x16x32_bf16(av, wv, dst, 0, 0, 0);
            }
        } else {
            f32x4 afr[32];
            const u16* pa = h0base + (size_t)((u32)(s + 1) & m0) * S_ELEMS
                          + (size_t)(b0 + r16) * HH + q8;   // y0[s]
            const u16* pb = h1base + (size_t)((u32)s & 1) * S_ELEMS
                          + (size_t)(b0 + r16) * HH + q8;   // h1[s-1]
            FragLd<0, 16>::go(afr + 16, pb);
            FragLd<0, 16>::go(afr, pa);
            asm volatile("s_waitcnt vmcnt(0)" ::: "memory");
            __builtin_amdgcn_sched_barrier(0);
            #pragma unroll
            for (int kt = 0; kt < 32; ++kt) {
                bf16x8 av = __builtin_bit_cast(bf16x8, afr[kt]);
                bf16x8 wv = __builtin_bit_cast(bf16x8, wf[kt]);
                f32x4& dst = (kt & 2) ? ((kt & 1) ? a3 : a2) : ((kt & 1) ? a1 : a0);
                dst = __builtin_amdgcn_mfma_f32_16x16x32_bf16(av, wv, dst, 0, 0, 0);
            }
        }
        f32x4 acc = (a0 + a1) + (a2 + a3);

        // gates for (myb, col): lanes sharing (quad,jj), gg = gate
        float gi = 0.f, gf = 0.f, gc = 0.f, go = 0.f;
        #pragma unroll
        for (int r = 0; r < 4; ++r) {
            float v0 = __shfl(acc[r], sl0, 64);
            float v1 = __shfl(acc[r], sl1, 64);
            float v2 = __shfl(acc[r], sl2, 64);
            float v3 = __shfl(acc[r], sl3, 64);
            if (r == gg) { gi = v0; gf = v1; gc = v2; go = v3; }
        }
        gi = sigf(gi + bi);
        gf = sigf(gf + bf_);
        gc = tanh_f(gc + bg);
        go = sigf(go + bo);
        c = gf * c + gi * gc;
        const float h = go * tanh_f(c);

        // h store: the only pre-flag store
        u16* hw = (LAYER == 0) ? (h0base + (size_t)((u32)(s + 1) & m0) * S_ELEMS)
                               : (h1base + (size_t)((u32)(s + 1) & 1) * S_ELEMS);
        st_h_sc(&hw[myb * HH + col], f2b_rne(h));

        // ---- arrival: drain h store, then raise own flag ----
        asm volatile("s_waitcnt vmcnt(0)" ::: "memory");
        __syncthreads();   // all waves of this block drained
        if (tid == 0)
            st_u32_sc(&slots[(u32)blockIdx.x * 32], (u32)(s + 1));

        // ---- shadow work (flies while peers finish / flags propagate) ----
        if (LAYER == 1) {
            out[(size_t)s * S_ELEMS + myb * HH + col] = h;
            if (s == TT - 1) {
                float* fin = out + Y_ELEMS + 2 * S_ELEMS;
                fin[myb * HH + col] = h;
                fin[S_ELEMS + myb * HH + col] = c;
            }
        } else {
            if (s == TT - 1) {
                float* fin = out + Y_ELEMS;
                fin[myb * HH + col] = h;
                fin[S_ELEMS + myb * HH + col] = c;
            }
            if (s + 1 < TT) {   // prefetch x[s+1] into registers
                const float* xp = x + ((size_t)(s + 1) * BB + b0 + r16) * CC + q8;
                #pragma unroll
                for (int kt = 0; kt < 8; ++kt) {
                    xf0[kt] = *(const float4*)(xp + kt * 32);
                    xf1[kt] = *(const float4*)(xp + kt * 32 + 4);
                }
            }
        }
    }

    // L1's last step needs gen0 >= TT: L0 aggregator publishes it post-loop.
    if (LAYER == 0 && AGG) {
        if (tid < 64) {
            const u32* p0 = slots + ((u32)(tid * 2 + 0)) * 32;
            const u32* p1 = slots + ((u32)(tid * 2 + 1)) * 32;
            u32 m;
            do {
                u32 va = ld_u32_sc(p0);
                u32 vb = ld_u32_sc(p1);
                m = min(va, vb);
            } while (m < (u32)TT);
        }
        __syncthreads();
        if (tid == 0) {
            #pragma unroll
            for (int k2 = 0; k2 < 4; ++k2) st_u32_sc(gen0 + k2 * 32, (u32)TT);
        }
    }
}

__global__ __launch_bounds__(256) __attribute__((amdgpu_waves_per_eu(1, 1)))
void k_lstm(const float* __restrict__ x,
            const float* __restrict__ c00,
            const float* __restrict__ c01,
            float* __restrict__ out,
            unsigned char* __restrict__ ws, u32 m0, u64 h1off) {
    const int bid = blockIdx.x;
    if (bid < 128) run_ticks<0>(x, c00, out, ws, bid, m0, h1off);
    else           run_ticks<1>(x, c01, out, ws, bid - 128, m0, h1off);
}

extern "C" void kernel_launch(void* const* d_in, const int* in_sizes, int n_in,
                              void* d_out, int out_size, void* d_ws, size_t ws_size,
                              hipStream_t stream) {
    const float* x    = (const float*)d_in[0];
    const float* h0_0 = (const float*)d_in[1];
    const float* c0_0 = (const float*)d_in[2];
    const float* h0_1 = (const float*)d_in[3];
    const float* c0_1 = (const float*)d_in[4];
    const float* Wih0 = (const float*)d_in[5];
    const float* Whh0 = (const float*)d_in[6];
    const float* bih0 = (const float*)d_in[7];
    const float* bhh0 = (const float*)d_in[8];
    const float* Wih1 = (const float*)d_in[9];
    const float* Whh1 = (const float*)d_in[10];
    const float* bih1 = (const float*)d_in[11];
    const float* bhh1 = (const float*)d_in[12];
    float* out = (float*)d_out;
    unsigned char* ws = (unsigned char*)d_ws;

    // 4-deep h0 ring (slack 3) needs h1 moved past WPK1: end 7,786,496.
    // Otherwise 2-deep (slack 1) in the proven R4 footprint (7,655,424).
    const u64 NEED4 = 7655424ull + 2ull * H_SLOT_BYTES;   // 7,786,496
    const bool big = (u64)ws_size >= NEED4;
    const u32 m0 = big ? 3u : 1u;
    const u64 h1off = big ? 7655424ull : 184320ull;

    k_init<<<128, 256, 0, stream>>>(bih0, bhh0, bih1, bhh1, h0_0, h0_1, ws, h1off);
    k_wprep<<<1792, 256, 0, stream>>>(Wih0, Whh0, Wih1, Whh1, ws);
    k_lstm<<<256, 256, 0, stream>>>(x, c0_0, c0_1, out, ws, m0, h1off);
}

// Round 11
// 5148.542 us; speedup vs baseline: 1.2625x; 1.2625x over previous
//
#include <hip/hip_runtime.h>

// ---------------------------------------------------------------------------
// Persistent weight-stationary LSTM, bf16 MFMA, R4 sync + coalesced h transport.
// T=1024 B=64 C=256 H=512, 2 layers, fp32 in/out.
//  - 256 blocks x 256 threads, 1 block/CU; blocks 0..127 = layer0 (step t),
//    128..255 = layer1 (step t-1); R4 flag barrier (block flags -> block0
//    wave-scan -> gen lines -> tid0 poll) -- unchanged (best measured).
//  - KEY CHANGE vs R4: h buffers re-laid out as [producer p][batch b] u64
//    (p = col>>2; same 64KB/slot). Producer packs its 4 consecutive cols of
//    a row into ONE u64 (3 shuffles) -> a wave's 16 stores are 128B
//    contiguous -> 2 full-line transactions (was 64 scattered 2B sc1 stores
//    per wave -> partial-line RMW at the memory side: the ~650KB/tick excess
//    in BOTH FETCH_SIZE and WRITE_SIZE, and an HBM-class vmcnt(0) drain on
//    the critical path every tick -- invariant across R4/R9/R10 sync nulls).
//  - Consumer A-frags: 8-col fragment spans two producers -> 2x 8B
//    global_load_dwordx2 sc0 sc1 (asm, forced-live, one LLC round). Wave
//    addresses per instruction are 128B-contiguous chunks: 8 lines/instr
//    vs 64 before (4x fewer read transactions). Same bits -> same math.
//  - mfma_f32_16x16x32_bf16: A[m=lane&15][k=quad*8+j], B(N,K)[n=lane&15][k=quad*8+j],
//    D[m=quad*4+reg][n=lane&15]  (guide-verified mapping, m90/m97 convention)
// ---------------------------------------------------------------------------

#define TT 1024
#define BB 64
#define CC 256
#define HH 512
#define Y_ELEMS (TT * BB * HH)
#define S_ELEMS (BB * HH)

typedef __attribute__((ext_vector_type(8))) short bf16x8;
typedef __attribute__((ext_vector_type(4))) float f32x4;
typedef unsigned int u32;
typedef unsigned short u16;
typedef unsigned long long u64;

// ---- ws layout (bytes) ----
#define WS_BAR 0           // 256 slots * 128B
#define WS_GEN 32768       // 4 gen lines * 128B
#define WS_BSUM0 36864     // 2048 f32
#define WS_BSUM1 45056     // 2048 f32
#define WS_H0 53248        // 2 * 65536 B  (h0 ping-pong, [128][64] u64)
#define WS_H1 184320       // 2 * 65536 B  (h1 ping-pong, [128][64] u64)
#define WS_WPK0 315392     // 128*24*64*8 bf16  (layer0 packed W)
#define WS_WPK1 3461120    // 128*32*64*8 bf16  (layer1 packed W)
// end 7655424 (~7.66 MB)

__device__ __forceinline__ u16 f2b_rne(float f) {
    u32 u = __float_as_uint(f);
    return (u16)((u + 0x7FFFu + ((u >> 16) & 1u)) >> 16);
}
__device__ __forceinline__ u16 f2b_fast(float f) {  // round-half-up, 2 ops
    return (u16)((__float_as_uint(f) + 0x8000u) >> 16);
}
__device__ __forceinline__ float sigf(float z) { return 1.0f / (1.0f + __expf(-z)); }
__device__ __forceinline__ float tanh_f(float z) { return 2.0f / (1.0f + __expf(-2.0f * z)) - 1.0f; }

__device__ __forceinline__ bf16x8 pack8(float4 a, float4 b) {
    union { u16 u[8]; bf16x8 v; } r;
    r.u[0] = f2b_fast(a.x); r.u[1] = f2b_fast(a.y); r.u[2] = f2b_fast(a.z); r.u[3] = f2b_fast(a.w);
    r.u[4] = f2b_fast(b.x); r.u[5] = f2b_fast(b.y); r.u[6] = f2b_fast(b.z); r.u[7] = f2b_fast(b.w);
    return r.v;
}

__device__ __forceinline__ u32 ld_u32_sc(const u32* p) {
    return __hip_atomic_load(p, __ATOMIC_RELAXED, __HIP_MEMORY_SCOPE_AGENT);
}
__device__ __forceinline__ void st_u32_sc(u32* p, u32 v) {
    __hip_atomic_store(p, v, __ATOMIC_RELAXED, __HIP_MEMORY_SCOPE_AGENT);
}

// ---- init: zero flags/gens, bsum = bih+bhh, h slot0 <- bf16(h_init), NEW layout ----
// [p][b] u64: element (b,col) -> u16 index (col>>2)*256 + b*4 + (col&3)
__global__ void k_init(const float* __restrict__ bih0, const float* __restrict__ bhh0,
                       const float* __restrict__ bih1, const float* __restrict__ bhh1,
                       const float* __restrict__ h00, const float* __restrict__ h01,
                       unsigned char* __restrict__ ws) {
    u32* bar = (u32*)(ws + WS_BAR);
    float* bs0 = (float*)(ws + WS_BSUM0);
    float* bs1 = (float*)(ws + WS_BSUM1);
    u16* h0 = (u16*)(ws + WS_H0);
    u16* h1 = (u16*)(ws + WS_H1);
    int t = blockIdx.x * 256 + threadIdx.x;  // 32768 threads
    if (t < 8448) bar[t] = 0u;               // slots + gen region
    if (t < 2048) { bs0[t] = bih0[t] + bhh0[t]; bs1[t] = bih1[t] + bhh1[t]; }
    if (t < S_ELEMS) {
        int b = t >> 9, col = t & 511;
        int no = ((col >> 2) << 8) + (b << 2) + (col & 3);
        h0[no] = f2b_rne(h00[t]);
        h1[no] = f2b_rne(h01[t]);
    }
}

// ---- weight pack: fp32 [4H,K] -> bf16 B-frag order wpk[bidL][kt][lane][8] ----
// rows permuted: n-index (lane&15) = gg*4+jj  <->  W row = gg*512 + bidL*4 + jj
__global__ void k_wprep(const float* __restrict__ Wih0, const float* __restrict__ Whh0,
                        const float* __restrict__ Wih1, const float* __restrict__ Whh1,
                        unsigned char* __restrict__ ws) {
    u16* wpk0 = (u16*)(ws + WS_WPK0);
    u16* wpk1 = (u16*)(ws + WS_WPK1);
    int u = blockIdx.x * 256 + threadIdx.x;  // 458752 threads
    const float* s;
    u16* d;
    if (u < 128 * 24 * 64) {  // layer0: 8 x-tiles (K=256) + 16 h-tiles (K=512)
        int bidL = u / (24 * 64);
        int kt = (u >> 6) % 24;
        int lane = u & 63;
        int n = lane & 15, quad = lane >> 4;
        int row = (n >> 2) * 512 + bidL * 4 + (n & 3);
        int k = kt * 32 + quad * 8;
        s = (k < 256) ? (Wih0 + (size_t)row * 256 + k) : (Whh0 + (size_t)row * 512 + (k - 256));
        d = wpk0 + (size_t)((bidL * 24 + kt) * 64 + lane) * 8;
    } else {  // layer1: 16 y0-tiles + 16 h1-tiles (K=1024)
        int v = u - 128 * 24 * 64;
        int bidL = v / (32 * 64);
        int kt = (v >> 6) % 32;
        int lane = v & 63;
        int n = lane & 15, quad = lane >> 4;
        int row = (n >> 2) * 512 + bidL * 4 + (n & 3);
        int k = kt * 32 + quad * 8;
        s = (k < 512) ? (Wih1 + (size_t)row * 512 + k) : (Whh1 + (size_t)row * 512 + (k - 512));
        d = wpk1 + (size_t)((bidL * 32 + kt) * 64 + lane) * 8;
    }
    #pragma unroll
    for (int i = 0; i < 8; ++i) d[i] = f2b_rne(s[i]);
}

// ---- the persistent tick loop, templated on layer ----
template <int LAYER>
__device__ void run_ticks(const float* __restrict__ x, const float* __restrict__ c0,
                          float* __restrict__ out, unsigned char* __restrict__ ws, int bidL) {
    constexpr int NKT = (LAYER == 0) ? 24 : 32;
    u32* slots = (u32*)(ws + WS_BAR);
    u32* gen = (u32*)(ws + WS_GEN);
    const float* bs = (const float*)(ws + (LAYER == 0 ? WS_BSUM0 : WS_BSUM1));
    u16* h0base = (u16*)(ws + WS_H0);    // 2 slots of S_ELEMS u16 ([128][64] u64)
    u16* h1base = (u16*)(ws + WS_H1);
    const u16* wpk = (const u16*)(ws + (LAYER == 0 ? WS_WPK0 : WS_WPK1));

    const int tid = threadIdx.x, lane = tid & 63, wave = tid >> 6;
    const int r16 = lane & 15, quad = lane >> 4, q8 = quad * 8;
    const int gg = r16 >> 2, jj = r16 & 3;
    const int b0 = wave * 16;
    const int col = bidL * 4 + jj;            // h column this lane finalizes
    const int myb = b0 + quad * 4 + gg;       // batch this lane finalizes
    const int sl0 = (quad << 4) | (0 << 2) | jj;
    const int sl1 = (quad << 4) | (1 << 2) | jj;
    const int sl2 = (quad << 4) | (2 << 2) | jj;
    const int sl3 = (quad << 4) | (3 << 2) | jj;
    const int baseln = (quad << 4) | (gg << 2);   // lane jj=0 of my (quad,gg) group

    // per-lane consumer chunk base offset (bytes): quad*1024 + rb*8
    const size_t cbase = (size_t)quad * 1024 + (size_t)(b0 + r16) * 8;

    // biases (hoisted), c state in register for the whole run
    const float bi = bs[0 * HH + col], bf_ = bs[1 * HH + col];
    const float bg = bs[2 * HH + col], bo = bs[3 * HH + col];
    float c = c0[myb * HH + col];

    // weight fragments: load once, pin (R4-identical)
    f32x4 wf[NKT];
    {
        const u16* wp = wpk + (size_t)(bidL * NKT * 64 + lane) * 8;
        #pragma unroll
        for (int kt = 0; kt < NKT; ++kt) wf[kt] = *(const f32x4*)(wp + (size_t)kt * 64 * 8);
        #pragma unroll
        for (int kt = 0; kt < NKT; ++kt) asm volatile("" : "+v"(wf[kt]));
    }

    // layer0: x prefetch registers (t=0 issued before the loop)
    float4 xf0[8], xf1[8];
    if (LAYER == 0) {
        const float* xp = x + (size_t)(b0 + r16) * CC + q8;
        #pragma unroll
        for (int kt = 0; kt < 8; ++kt) {
            xf0[kt] = *(const float4*)(xp + kt * 32);
            xf1[kt] = *(const float4*)(xp + kt * 32 + 4);
        }
    }

    for (int i = 0; i <= TT; ++i) {
        const bool active = (LAYER == 0) ? (i < TT) : (i >= 1);
        const int t = (LAYER == 0) ? i : i - 1;
        float h = 0.f;
        if (active) {
            f32x4 a0 = {0.f,0.f,0.f,0.f}, a1 = {0.f,0.f,0.f,0.f};
            f32x4 a2 = {0.f,0.f,0.f,0.f}, a3 = {0.f,0.f,0.f,0.f};
            if (LAYER == 0) {
                // 16 frags = 32x 8B loads, one LLC round (frag kt: cols q8+32kt..+7
                // live at producers p=2q+8kt, p+1 -> bytes kt*4096 / +512 from cbase)
                u64 alo[16], ahi[16];
                {
                    const char* hb = (const char*)(h0base + (size_t)(t & 1) * S_ELEMS) + cbase;
                    #pragma unroll
                    for (int kt = 0; kt < 16; ++kt) {
                        const char* pk = hb + kt * 4096;
                        asm volatile("global_load_dwordx2 %0, %1, off sc0 sc1"
                                     : "=&v"(alo[kt]) : "v"(pk) : "memory");
                        asm volatile("global_load_dwordx2 %0, %1, off offset:512 sc0 sc1"
                                     : "=&v"(ahi[kt]) : "v"(pk) : "memory");
                    }
                }
                // x projection from prefetched registers overlaps the h-load flight
                #pragma unroll
                for (int kt = 0; kt < 8; ++kt) {
                    bf16x8 a = pack8(xf0[kt], xf1[kt]);
                    bf16x8 wv = __builtin_bit_cast(bf16x8, wf[kt]);
                    f32x4& dst = (kt & 2) ? ((kt & 1) ? a3 : a2) : ((kt & 1) ? a1 : a0);
                    dst = __builtin_amdgcn_mfma_f32_16x16x32_bf16(a, wv, dst, 0, 0, 0);
                }
                asm volatile("s_waitcnt vmcnt(0)" ::: "memory");
                __builtin_amdgcn_sched_barrier(0);
                #pragma unroll
                for (int kt = 0; kt < 16; ++kt) {
                    union { u64 q[2]; bf16x8 v; } fa;
                    fa.q[0] = alo[kt]; fa.q[1] = ahi[kt];
                    bf16x8 wv = __builtin_bit_cast(bf16x8, wf[8 + kt]);
                    f32x4& dst = (kt & 2) ? ((kt & 1) ? a3 : a2) : ((kt & 1) ? a1 : a0);
                    dst = __builtin_amdgcn_mfma_f32_16x16x32_bf16(fa.v, wv, dst, 0, 0, 0);
                }
            } else {
                // y0[t] = h0 slot (t+1)&1; h1 prev = slot t&1 (both new layout)
                u64 plo[16], phi[16], qlo[16], qhi[16];
                {
                    const char* ha = (const char*)(h0base + (size_t)((t + 1) & 1) * S_ELEMS) + cbase;
                    const char* hb = (const char*)(h1base + (size_t)(t & 1) * S_ELEMS) + cbase;
                    #pragma unroll
                    for (int kt = 0; kt < 16; ++kt) {     // h1 first (R4 order)
                        const char* pk = hb + kt * 4096;
                        asm volatile("global_load_dwordx2 %0, %1, off sc0 sc1"
                                     : "=&v"(qlo[kt]) : "v"(pk) : "memory");
                        asm volatile("global_load_dwordx2 %0, %1, off offset:512 sc0 sc1"
                                     : "=&v"(qhi[kt]) : "v"(pk) : "memory");
                    }
                    #pragma unroll
                    for (int kt = 0; kt < 16; ++kt) {
                        const char* pk = ha + kt * 4096;
                        asm volatile("global_load_dwordx2 %0, %1, off sc0 sc1"
                                     : "=&v"(plo[kt]) : "v"(pk) : "memory");
                        asm volatile("global_load_dwordx2 %0, %1, off offset:512 sc0 sc1"
                                     : "=&v"(phi[kt]) : "v"(pk) : "memory");
                    }
                }
                asm volatile("s_waitcnt vmcnt(0)" ::: "memory");
                __builtin_amdgcn_sched_barrier(0);
                #pragma unroll
                for (int kt = 0; kt < 32; ++kt) {
                    union { u64 q[2]; bf16x8 v; } fa;
                    if (kt < 16) { fa.q[0] = plo[kt]; fa.q[1] = phi[kt]; }
                    else         { fa.q[0] = qlo[kt - 16]; fa.q[1] = qhi[kt - 16]; }
                    bf16x8 wv = __builtin_bit_cast(bf16x8, wf[kt]);
                    f32x4& dst = (kt & 2) ? ((kt & 1) ? a3 : a2) : ((kt & 1) ? a1 : a0);
                    dst = __builtin_amdgcn_mfma_f32_16x16x32_bf16(fa.v, wv, dst, 0, 0, 0);
                }
            }
            f32x4 acc = (a0 + a1) + (a2 + a3);

            // gates for (myb, col): lanes sharing (quad,jj), gg = gate
            float gi = 0.f, gf = 0.f, gc = 0.f, go = 0.f;
            #pragma unroll
            for (int r = 0; r < 4; ++r) {
                float v0 = __shfl(acc[r], sl0, 64);
                float v1 = __shfl(acc[r], sl1, 64);
                float v2 = __shfl(acc[r], sl2, 64);
                float v3 = __shfl(acc[r], sl3, 64);
                if (r == gg) { gi = v0; gf = v1; gc = v2; go = v3; }
            }
            gi = sigf(gi + bi);
            gf = sigf(gf + bf_);
            gc = tanh_f(gc + bg);
            go = sigf(go + bo);
            c = gf * c + gi * gc;
            h = go * tanh_f(c);

            // ---- coalesced h store: pack 4 cols of row myb into one u64 ----
            u32 w0 = f2b_rne(h);
            u32 w1 = (u32)__shfl((int)w0, baseln + 1, 64);
            u32 w2 = (u32)__shfl((int)w0, baseln + 2, 64);
            u32 w3 = (u32)__shfl((int)w0, baseln + 3, 64);
            if (jj == 0) {
                u64 pkd = (u64)(w0 | (w1 << 16)) | ((u64)(w2 | (w3 << 16)) << 32);
                u64* hw = (u64*)((LAYER == 0 ? h0base : h1base)
                                 + (size_t)((t + 1) & 1) * S_ELEMS)
                          + (size_t)bidL * 64 + myb;
                __hip_atomic_store(hw, pkd, __ATOMIC_RELAXED, __HIP_MEMORY_SCOPE_AGENT);
            }
        }
        // ---- barrier arrival: drain h store, then raise flag ----
        if (i < TT) {
            asm volatile("s_waitcnt vmcnt(0)" ::: "memory");
            __syncthreads();   // all waves of this block drained
            if (tid == 0)
                st_u32_sc(&slots[(u32)blockIdx.x * 32], (u32)(i + 1));
        }
        // ---- shadow work while flags propagate / peers finish ----
        if (active) {
            if (LAYER == 1) out[(size_t)t * S_ELEMS + myb * HH + col] = h;
            if (t == TT - 1) {
                float* fin = out + Y_ELEMS + (LAYER == 0 ? 0 : 2) * S_ELEMS;
                fin[myb * HH + col] = h;
                fin[S_ELEMS + myb * HH + col] = c;
            }
        }
        if (LAYER == 0 && i + 1 < TT) {      // prefetch x[t+1] into registers
            const float* xp = x + ((size_t)(i + 1) * BB + b0 + r16) * CC + q8;
            #pragma unroll
            for (int kt = 0; kt < 8; ++kt) {
                xf0[kt] = *(const float4*)(xp + kt * 32);
                xf1[kt] = *(const float4*)(xp + kt * 32 + 4);
            }
        }
        // ---- barrier completion: aggregator (block 0) or gen-poll (others) ----
        if (i < TT) {
            const u32 tgt = (u32)(i + 1);
            if (blockIdx.x == 0) {
                if (tid < 64) {  // wave 0 scans all 256 slots, 4 per lane
                    const u32* p0 = slots + ((u32)tid * 4 + 0) * 32;
                    const u32* p1 = slots + ((u32)tid * 4 + 1) * 32;
                    const u32* p2 = slots + ((u32)tid * 4 + 2) * 32;
                    const u32* p3 = slots + ((u32)tid * 4 + 3) * 32;
                    u32 m;
                    do {
                        u32 va = ld_u32_sc(p0);
                        u32 vb = ld_u32_sc(p1);
                        u32 vc = ld_u32_sc(p2);
                        u32 vd = ld_u32_sc(p3);
                        m = min(min(va, vb), min(vc, vd));
                    } while (m < tgt);
                }
                __syncthreads();
                if (tid == 0) {
                    #pragma unroll
                    for (int k2 = 0; k2 < 4; ++k2) st_u32_sc(gen + k2 * 32, tgt);
                }
            } else {
                if (tid == 0) {
                    const u32* gp = gen + ((u32)blockIdx.x & 3) * 32;
                    while (ld_u32_sc(gp) < tgt) { }
                }
                __syncthreads();
            }
        }
    }
}

__global__ __launch_bounds__(256) __attribute__((amdgpu_waves_per_eu(1, 1)))
void k_lstm(const float* __restrict__ x,
            const float* __restrict__ c00,
            const float* __restrict__ c01,
            float* __restrict__ out,
            unsigned char* __restrict__ ws) {
    const int bid = blockIdx.x;
    if (bid < 128) run_ticks<0>(x, c00, out, ws, bid);
    else           run_ticks<1>(x, c01, out, ws, bid - 128);
}

extern "C" void kernel_launch(void* const* d_in, const int* in_sizes, int n_in,
                              void* d_out, int out_size, void* d_ws, size_t ws_size,
                              hipStream_t stream) {
    const float* x    = (const float*)d_in[0];
    const float* h0_0 = (const float*)d_in[1];
    const float* c0_0 = (const float*)d_in[2];
    const float* h0_1 = (const float*)d_in[3];
    const float* c0_1 = (const float*)d_in[4];
    const float* Wih0 = (const float*)d_in[5];
    const float* Whh0 = (const float*)d_in[6];
    const float* bih0 = (const float*)d_in[7];
    const float* bhh0 = (const float*)d_in[8];
    const float* Wih1 = (const float*)d_in[9];
    const float* Whh1 = (const float*)d_in[10];
    const float* bih1 = (const float*)d_in[11];
    const float* bhh1 = (const float*)d_in[12];
    float* out = (float*)d_out;
    unsigned char* ws = (unsigned char*)d_ws;

    k_init<<<128, 256, 0, stream>>>(bih0, bhh0, bih1, bhh1, h0_0, h0_1, ws);
    k_wprep<<<1792, 256, 0, stream>>>(Wih0, Whh0, Wih1, Whh1, ws);
    k_lstm<<<256, 256, 0, stream>>>(x, c0_0, c0_1, out, ws);
}